// Round 7
// baseline (7971.937 us; speedup 1.0000x reference)
//
#include <hip/hip_runtime.h>

// OptNet KKT layer: out = normalize(M^{-1} K^T), M = c1*Phi + c2*I (SPD, n=4096, 512 RHS).
// Blocked fp32 Cholesky with lookahead. R7: full-row (512B) staging for all panel reads
// (R6 counters showed syrk HBM-bound at 290 GB/s due to 64B strided fragments),
// XCD-chunked block swizzle for L2 panel reuse, rebuilt 16-wide potrf role.

#define N    4096
#define NRHS 512
#define NB   128
#define TSTR2 132  // LDS tile stride (floats), %4==0 keeps b128 alignment
#define TSTR 136   // chunk staging stride (solve kernels)
#define BSTR 68    // 64-wide RHS tile stride

__device__ __forceinline__ int xcd_map(int bid, int nwg) {
  // bijective: hw bids on the same XCD (bid%8) -> contiguous logical ids (m204)
  int x = bid & 7, i = bid >> 3;
  int q = nwg >> 3, r = nwg & 7;
  return (x < r ? x * (q + 1) : r * (q + 1) + (x - r) * q) + i;
}

// stage 128x128 tile g[row0..][col0..] into t-major LDS: T[t*TSTR2+r] = g[row0+r][col0+t]
__device__ __forceinline__ void stage_tmajor(const float* __restrict__ g,
                                             int row0, int col0,
                                             float* __restrict__ T, int tid) {
#pragma unroll
  for (int i = 0; i < 16; ++i) {
    int idx = tid + (i << 8);
    int r = idx >> 5, fx = idx & 31;
    const float4 v = *(const float4*)(g + (size_t)(row0 + r) * N + col0 + 4 * fx);
    int c4 = 4 * fx;
    T[(c4 + 0) * TSTR2 + r] = v.x;
    T[(c4 + 1) * TSTR2 + r] = v.y;
    T[(c4 + 2) * TSTR2 + r] = v.z;
    T[(c4 + 3) * TSTR2 + r] = v.w;
  }
}

// ---------------- scalars ----------------
__global__ __launch_bounds__(256) void k_scalars(const float* __restrict__ imp,
                                                 const float* __restrict__ exc,
                                                 const float* __restrict__ gamma,
                                                 float* __restrict__ c) {
  __shared__ float red[256];
  int tid = threadIdx.x;
  float s = 0.0f;
  for (int i = tid; i < 1024; i += 256) { float x = imp[i], y = exc[i]; s += x * x + y * y; }
  red[tid] = s; __syncthreads();
  for (int w = 128; w > 0; w >>= 1) { if (tid < w) red[tid] += red[tid + w]; __syncthreads(); }
  if (tid == 0) { c[0] = red[0] / 512.0f; c[1] = gamma[0] / 512.0f; }
}

// ---------------- M = c1*Phi + c2*I ----------------
__global__ __launch_bounds__(256) void k_build_M(const float* __restrict__ Phi,
                                                 const float* __restrict__ c,
                                                 float* __restrict__ M) {
  int idx = blockIdx.x * 256 + threadIdx.x;
  int base = idx * 4;
  float4 p = *(const float4*)(Phi + base);
  float c1 = c[0], c2 = c[1];
  float4 m;
  m.x = c1 * p.x; m.y = c1 * p.y; m.z = c1 * p.z; m.w = c1 * p.w;
  int r = base >> 12, c0 = base & (N - 1);
  if (r == c0)     m.x += c2;
  if (r == c0 + 1) m.y += c2;
  if (r == c0 + 2) m.z += c2;
  if (r == c0 + 3) m.w += c2;
  *(float4*)(M + base) = m;
}

// ---------------- S[i][b] = K[b][i] ----------------
__global__ __launch_bounds__(256) void k_transpose(const float* __restrict__ K,
                                                   float* __restrict__ S) {
  __shared__ float t[32][33];
  int bi = blockIdx.x, bb = blockIdx.y;
  int tx = threadIdx.x & 31, ty = threadIdx.x >> 5;
  for (int r = 0; r < 4; ++r)
    t[ty + 8 * r][tx] = K[(size_t)(bb * 32 + ty + 8 * r) * N + bi * 32 + tx];
  __syncthreads();
  for (int r = 0; r < 4; ++r)
    S[(size_t)(bi * 32 + ty + 8 * r) * NRHS + bb * 32 + tx] = t[tx][ty + 8 * r];
}

// ---------------- fused syrk(panel k0) + lookahead potrf(kdiag) ----------------
// 256 threads. logical block 0: potrf role; >=1: trailing syrk tile (lower tri).
__global__ __launch_bounds__(256, 1) void k_syrk_potrf(float* __restrict__ M,
                                                       float* __restrict__ U,
                                                       float* __restrict__ UT,
                                                       int kdiag, int k0) {
  __shared__ float shA[NB * TSTR2];   // syrk Pa / potrf panel, later Us
  __shared__ float shB[NB * TSTR2];   // syrk Pb / potrf Lb (row-major)
  __shared__ float dinv[NB];
  __shared__ float Wl[7][16][18];
  int tid = threadIdx.x;
  int p = (gridDim.x > 1) ? xcd_map(blockIdx.x, gridDim.x) : 0;
  int rr = (tid >> 4) * 8, cc = (tid & 15) * 8;

  if (p > 0) {
    // ================= syrk role: C(br,bc) -= P_br P_bc^T =================
    int br = (int)((sqrtf(8.f * (float)p + 1.f) - 1.f) * 0.5f);
    while (((br + 1) * (br + 2)) / 2 <= p) ++br;
    while ((br * (br + 1)) / 2 > p) --br;
    int bc = p - (br * (br + 1)) / 2;
    int t0 = kdiag * NB;
    int r0 = t0 + br * NB, c0 = t0 + bc * NB;
    stage_tmajor(M, r0, k0, shA, tid);
    stage_tmajor(M, c0, k0, shB, tid);
    __syncthreads();
    float acc[8][8] = {};
#pragma unroll 2
    for (int t = 0; t < NB; ++t) {
      const float4 a0 = *(const float4*)&shA[t * TSTR2 + rr];
      const float4 a1 = *(const float4*)&shA[t * TSTR2 + rr + 4];
      const float4 b0 = *(const float4*)&shB[t * TSTR2 + cc];
      const float4 b1 = *(const float4*)&shB[t * TSTR2 + cc + 4];
      float av[8] = {a0.x, a0.y, a0.z, a0.w, a1.x, a1.y, a1.z, a1.w};
      float bv[8] = {b0.x, b0.y, b0.z, b0.w, b1.x, b1.y, b1.z, b1.w};
#pragma unroll
      for (int q = 0; q < 8; ++q)
#pragma unroll
        for (int w = 0; w < 8; ++w) acc[q][w] += av[q] * bv[w];
    }
    for (int q = 0; q < 8; ++q) {
      float* mp = M + (size_t)(r0 + rr + q) * N + c0 + cc;
      float4 x0 = *(float4*)mp, x1 = *((float4*)mp + 1);
      x0.x -= acc[q][0]; x0.y -= acc[q][1]; x0.z -= acc[q][2]; x0.w -= acc[q][3];
      x1.x -= acc[q][4]; x1.y -= acc[q][5]; x1.z -= acc[q][6]; x1.w -= acc[q][7];
      *(float4*)mp = x0; *((float4*)mp + 1) = x1;
    }
    return;
  }

  // ================= potrf role =================
  int kr = kdiag * NB;
  float accd[8][8] = {};
  // stage diag tile row-major into shB
#pragma unroll
  for (int i = 0; i < 16; ++i) {
    int idx = tid + (i << 8);
    int r = idx >> 5, fx = idx & 31;
    *(float4*)&shB[r * TSTR2 + 4 * fx] =
        *(const float4*)(M + (size_t)(kr + r) * N + kr + 4 * fx);
  }
  if (k0 >= 0) {
    stage_tmajor(M, kr, k0, shA, tid);   // panel P(kdiag)
    __syncthreads();
#pragma unroll 2
    for (int t = 0; t < NB; ++t) {
      const float4 a0 = *(const float4*)&shA[t * TSTR2 + rr];
      const float4 a1 = *(const float4*)&shA[t * TSTR2 + rr + 4];
      const float4 b0 = *(const float4*)&shA[t * TSTR2 + cc];
      const float4 b1 = *(const float4*)&shA[t * TSTR2 + cc + 4];
      float av[8] = {a0.x, a0.y, a0.z, a0.w, a1.x, a1.y, a1.z, a1.w};
      float bv[8] = {b0.x, b0.y, b0.z, b0.w, b1.x, b1.y, b1.z, b1.w};
#pragma unroll
      for (int q = 0; q < 8; ++q)
#pragma unroll
        for (int w = 0; w < 8; ++w) accd[q][w] += av[q] * bv[w];
    }
    __syncthreads();
    for (int q = 0; q < 8; ++q) {
      shB[(rr + q) * TSTR2 + cc + 0] -= accd[q][0];
      shB[(rr + q) * TSTR2 + cc + 1] -= accd[q][1];
      shB[(rr + q) * TSTR2 + cc + 2] -= accd[q][2];
      shB[(rr + q) * TSTR2 + cc + 3] -= accd[q][3];
      shB[(rr + q) * TSTR2 + cc + 4] -= accd[q][4];
      shB[(rr + q) * TSTR2 + cc + 5] -= accd[q][5];
      shB[(rr + q) * TSTR2 + cc + 6] -= accd[q][6];
      shB[(rr + q) * TSTR2 + cc + 7] -= accd[q][7];
    }
  }
  __syncthreads();
  // zero shA (becomes Us)
  {
    float4* a4 = (float4*)shA;
    for (int i = tid; i < NB * TSTR2 / 4; i += 256) a4[i] = make_float4(0.f, 0.f, 0.f, 0.f);
  }
  __syncthreads();

  // ---- factorization: 8 panels of 16 ----
  int l = tid;
#pragma unroll 1
  for (int pp = 0; pp < 8; ++pp) {
    const int b0 = 16 * pp;
    if (tid < 16) {
      float r[16];
#pragma unroll
      for (int t = 0; t < 16; ++t) r[t] = shB[(b0 + l) * TSTR2 + b0 + t];
#pragma unroll
      for (int j = 0; j < 16; ++j) {
        float d = __shfl(r[j], j);
        float inv = rsqrtf(d);
        if (l == j) r[j] = d * inv;
        else if (l > j) r[j] *= inv;
        if (l == 0) dinv[b0 + j] = inv;
#pragma unroll
        for (int t = j + 1; t < 16; ++t) {
          float Ltj = __shfl(r[j], t);
          if (l >= t) r[t] -= r[j] * Ltj;
        }
      }
#pragma unroll
      for (int t = 0; t < 16; ++t) if (t <= l) shB[(b0 + l) * TSTR2 + b0 + t] = r[t];
    }
    __syncthreads();
    const int base = b0 + 16, nbl = NB - base;
    if (nbl > 0) {
      if (tid < nbl) {  // row TRSM, one row per thread
        const int r = base + tid;
        float xr[16];
#pragma unroll
        for (int j = 0; j < 16; ++j) {
          float v = shB[r * TSTR2 + b0 + j];
#pragma unroll
          for (int t = 0; t < 16; ++t) if (t < j) v -= xr[t] * shB[(b0 + j) * TSTR2 + b0 + t];
          xr[j] = v * dinv[b0 + j];
          shB[r * TSTR2 + b0 + j] = xr[j];
        }
      }
      __syncthreads();
      // rank-16 trailing (lower incl diag)
      const int tot = nbl * nbl;
      for (int idx = tid; idx < tot; idx += 256) {
        const int i = idx / nbl, j = idx - i * nbl;
        if (j <= i) {
          const float* ai = &shB[(base + i) * TSTR2 + b0];
          const float* bj = &shB[(base + j) * TSTR2 + b0];
          float4 a0 = *(const float4*)ai,      a1 = *(const float4*)(ai + 4);
          float4 a2 = *(const float4*)(ai + 8), a3 = *(const float4*)(ai + 12);
          float4 c0 = *(const float4*)bj,      c1 = *(const float4*)(bj + 4);
          float4 c2 = *(const float4*)(bj + 8), c3 = *(const float4*)(bj + 12);
          float s = a0.x*c0.x + a0.y*c0.y + a0.z*c0.z + a0.w*c0.w
                  + a1.x*c1.x + a1.y*c1.y + a1.z*c1.z + a1.w*c1.w
                  + a2.x*c2.x + a2.y*c2.y + a2.z*c2.z + a2.w*c2.w
                  + a3.x*c3.x + a3.y*c3.y + a3.z*c3.z + a3.w*c3.w;
          shB[(base + i) * TSTR2 + base + j] -= s;
        }
      }
      __syncthreads();
    }
  }

  // ---- 8 corner inverses in parallel (lanes 0..127): V_c into Us diag ----
  if (tid < 128) {
    const int cg = tid >> 4, g = tid & 15, b0 = 16 * cg;
    float x[16];
#pragma unroll
    for (int i = 0; i < 16; ++i) {
      float s = (g == i) ? 1.0f : 0.0f;
#pragma unroll
      for (int t = 0; t < 16; ++t) if (t < i) s -= shB[(b0 + i) * TSTR2 + b0 + t] * x[t];
      x[i] = s * dinv[b0 + i];
    }
#pragma unroll
    for (int i = 0; i < 16; ++i) shA[(b0 + i) * TSTR2 + b0 + g] = x[i];
  }
  __syncthreads();

  // ---- off-diag U blocks by diagonals: U_ij = -V_i * (sum_t L_it U_tj) ----
#pragma unroll 1
  for (int d = 1; d <= 7; ++d) {
    const int nb = 8 - d;
    for (int e = tid; e < nb * 256; e += 256) {
      const int blk = e >> 8, el = e & 255;
      const int bi = blk + d, bj = blk;
      const int r2 = el >> 4, c2 = el & 15;
      float s = 0.f;
      for (int t = 16 * bj; t < 16 * bi; ++t)
        s += shB[(16 * bi + r2) * TSTR2 + t] * shA[t * TSTR2 + 16 * bj + c2];
      Wl[blk][r2][c2] = s;
    }
    __syncthreads();
    for (int e = tid; e < nb * 256; e += 256) {
      const int blk = e >> 8, el = e & 255;
      const int bi = blk + d, bj = blk;
      const int r2 = el >> 4, c2 = el & 15;
      float s = 0.f;
#pragma unroll
      for (int t = 0; t < 16; ++t)
        s += shA[(16 * bi + r2) * TSTR2 + 16 * bi + t] * Wl[blk][t][c2];
      shA[(16 * bi + r2) * TSTR2 + 16 * bj + c2] = -s;
    }
    __syncthreads();
  }

  // ---- write L, U, UT ----
#pragma unroll
  for (int i2 = 0; i2 < 16; ++i2) {
    int idx = tid + (i2 << 8);
    int i = idx >> 5, f = idx & 31;
    *(float4*)(M + (size_t)(kr + i) * N + kr + 4 * f) = *(const float4*)&shB[i * TSTR2 + 4 * f];
    *(float4*)(U + (size_t)i * NB + 4 * f) = *(const float4*)&shA[i * TSTR2 + 4 * f];
    float4 v;
    v.x = shA[(4 * f + 0) * TSTR2 + i]; v.y = shA[(4 * f + 1) * TSTR2 + i];
    v.z = shA[(4 * f + 2) * TSTR2 + i]; v.w = shA[(4 * f + 3) * TSTR2 + i];
    *(float4*)(UT + (size_t)i * NB + 4 * f) = v;
  }
}

// ---------------- panel TRSM as GEMM: P := P_old * U^T ----------------
__global__ __launch_bounds__(256, 1) void k_trsm(float* __restrict__ M,
                                                 const float* __restrict__ UT, int k0) {
  __shared__ float shU[NB * TSTR2];   // t-major: shU[t][j] = U[j][t]
  __shared__ float shA[NB * TSTR2];   // t-major A tile
  int tid = threadIdx.x;
  int r0 = k0 + NB + blockIdx.x * NB;
#pragma unroll
  for (int i = 0; i < 16; ++i) {       // UT rows are already t-major, contiguous 512B
    int idx = tid + (i << 8);
    int t = idx >> 5, fx = idx & 31;
    *(float4*)&shU[t * TSTR2 + 4 * fx] = *(const float4*)(UT + (size_t)t * NB + 4 * fx);
  }
  stage_tmajor(M, r0, k0, shA, tid);
  __syncthreads();
  int i0 = (tid >> 4) * 8, j0 = (tid & 15) * 8;
  float acc[8][8] = {};
#pragma unroll 2
  for (int t = 0; t < NB; ++t) {
    const float4 a0 = *(const float4*)&shA[t * TSTR2 + i0];
    const float4 a1 = *(const float4*)&shA[t * TSTR2 + i0 + 4];
    const float4 u0 = *(const float4*)&shU[t * TSTR2 + j0];
    const float4 u1 = *(const float4*)&shU[t * TSTR2 + j0 + 4];
    float av[8] = {a0.x, a0.y, a0.z, a0.w, a1.x, a1.y, a1.z, a1.w};
    float uv[8] = {u0.x, u0.y, u0.z, u0.w, u1.x, u1.y, u1.z, u1.w};
#pragma unroll
    for (int q = 0; q < 8; ++q)
#pragma unroll
      for (int w = 0; w < 8; ++w) acc[q][w] += av[q] * uv[w];
  }
  for (int q = 0; q < 8; ++q) {
    float* mp = M + (size_t)(r0 + i0 + q) * N + k0 + j0;
    float4 x0 = {acc[q][0], acc[q][1], acc[q][2], acc[q][3]};
    float4 x1 = {acc[q][4], acc[q][5], acc[q][6], acc[q][7]};
    *(float4*)mp = x0; *((float4*)mp + 1) = x1;
  }
}

// ---------------- fused forward solve step k (1-D grid, XCD-chunked) ----------------
__global__ __launch_bounds__(256) void k_fsolve(float* __restrict__ S,
                                                float* __restrict__ X,
                                                const float* __restrict__ M,
                                                const float* __restrict__ UTk,
                                                int k0) {
  __shared__ float Xl[NB][BSTR];
  __shared__ float Aa[16][TSTR];
  __shared__ float Bb[16][BSTR];
  int tid = threadIdx.x;
  int id = xcd_map(blockIdx.x, gridDim.x);
  int d = id >> 3;
  int b0 = (id & 7) * 64;
  int i0g = k0 + d * NB;
  int ii = (tid >> 3) * 4, bl = (tid & 7) * 8;
  float acc[4][8] = {};
  for (int tch = 0; tch < NB; tch += 16) {
    for (int idx = tid; idx < 512; idx += 256) {
      int t = idx >> 5, f = idx & 31;
      *(float4*)&Aa[t][4 * f] = *(const float4*)(UTk + (size_t)(tch + t) * NB + 4 * f);
    }
    {
      int t = tid >> 4, f = tid & 15;
      *(float4*)&Bb[t][4 * f] = *(const float4*)(S + (size_t)(k0 + tch + t) * NRHS + b0 + 4 * f);
    }
    __syncthreads();
#pragma unroll 4
    for (int t = 0; t < 16; ++t) {
      float4 a0 = *(const float4*)&Aa[t][ii];
      float4 b0v = *(const float4*)&Bb[t][bl];
      float4 b1v = *(const float4*)&Bb[t][bl + 4];
      float av[4] = {a0.x, a0.y, a0.z, a0.w};
      float bv[8] = {b0v.x, b0v.y, b0v.z, b0v.w, b1v.x, b1v.y, b1v.z, b1v.w};
#pragma unroll
      for (int q = 0; q < 4; ++q)
#pragma unroll
        for (int w = 0; w < 8; ++w) acc[q][w] += av[q] * bv[w];
    }
    __syncthreads();
  }
  if (d == 0) {
    for (int q = 0; q < 4; ++q) {
      float* xp = X + (size_t)(k0 + ii + q) * NRHS + b0 + bl;
      float4 x0 = {acc[q][0], acc[q][1], acc[q][2], acc[q][3]};
      float4 x1 = {acc[q][4], acc[q][5], acc[q][6], acc[q][7]};
      *(float4*)xp = x0; *((float4*)xp + 1) = x1;
    }
    return;
  }
  for (int q = 0; q < 4; ++q) {
    float4 x0 = {acc[q][0], acc[q][1], acc[q][2], acc[q][3]};
    float4 x1 = {acc[q][4], acc[q][5], acc[q][6], acc[q][7]};
    *(float4*)&Xl[ii + q][bl] = x0; *(float4*)&Xl[ii + q][bl + 4] = x1;
  }
  __syncthreads();
  float acc2[4][8] = {};
  for (int tch = 0; tch < NB; tch += 16) {
    for (int idx = tid; idx < 512; idx += 256) {
      int r = idx >> 2, q = idx & 3;
      const float4 v = *(const float4*)(M + (size_t)(i0g + r) * N + k0 + tch + 4 * q);
      Aa[4 * q + 0][r] = v.x; Aa[4 * q + 1][r] = v.y;
      Aa[4 * q + 2][r] = v.z; Aa[4 * q + 3][r] = v.w;
    }
    __syncthreads();
#pragma unroll 4
    for (int t = 0; t < 16; ++t) {
      float4 a0 = *(const float4*)&Aa[t][ii];
      float4 b0v = *(const float4*)&Xl[tch + t][bl];
      float4 b1v = *(const float4*)&Xl[tch + t][bl + 4];
      float av[4] = {a0.x, a0.y, a0.z, a0.w};
      float bv[8] = {b0v.x, b0v.y, b0v.z, b0v.w, b1v.x, b1v.y, b1v.z, b1v.w};
#pragma unroll
      for (int q = 0; q < 4; ++q)
#pragma unroll
        for (int w = 0; w < 8; ++w) acc2[q][w] += av[q] * bv[w];
    }
    __syncthreads();
  }
  for (int q = 0; q < 4; ++q) {
    float* sp = S + (size_t)(i0g + ii + q) * NRHS + b0 + bl;
    float4 x0 = *(float4*)sp, x1 = *((float4*)sp + 1);
    x0.x -= acc2[q][0]; x0.y -= acc2[q][1]; x0.z -= acc2[q][2]; x0.w -= acc2[q][3];
    x1.x -= acc2[q][4]; x1.y -= acc2[q][5]; x1.z -= acc2[q][6]; x1.w -= acc2[q][7];
    *(float4*)sp = x0; *((float4*)sp + 1) = x1;
  }
}

// ---------------- fused backward solve step k (1-D grid, XCD-chunked) ----------------
__global__ __launch_bounds__(256) void k_bsolve(float* __restrict__ X,
                                                float* __restrict__ S,
                                                const float* __restrict__ M,
                                                const float* __restrict__ Uk,
                                                int k0) {
  __shared__ float Xl[NB][BSTR];
  __shared__ float Aa[16][TSTR];
  __shared__ float Bb[16][BSTR];
  int tid = threadIdx.x;
  int id = xcd_map(blockIdx.x, gridDim.x);
  int d = id >> 3;
  int b0 = (id & 7) * 64;
  int i0g = k0 - d * NB;
  int ii = (tid >> 3) * 4, bl = (tid & 7) * 8;
  float acc[4][8] = {};
  for (int tch = 0; tch < NB; tch += 16) {
    for (int idx = tid; idx < 512; idx += 256) {
      int t = idx >> 5, f = idx & 31;
      *(float4*)&Aa[t][4 * f] = *(const float4*)(Uk + (size_t)(tch + t) * NB + 4 * f);
    }
    {
      int t = tid >> 4, f = tid & 15;
      *(float4*)&Bb[t][4 * f] = *(const float4*)(X + (size_t)(k0 + tch + t) * NRHS + b0 + 4 * f);
    }
    __syncthreads();
#pragma unroll 4
    for (int t = 0; t < 16; ++t) {
      float4 a0 = *(const float4*)&Aa[t][ii];
      float4 b0v = *(const float4*)&Bb[t][bl];
      float4 b1v = *(const float4*)&Bb[t][bl + 4];
      float av[4] = {a0.x, a0.y, a0.z, a0.w};
      float bv[8] = {b0v.x, b0v.y, b0v.z, b0v.w, b1v.x, b1v.y, b1v.z, b1v.w};
#pragma unroll
      for (int q = 0; q < 4; ++q)
#pragma unroll
        for (int w = 0; w < 8; ++w) acc[q][w] += av[q] * bv[w];
    }
    __syncthreads();
  }
  if (d == 0) {
    for (int q = 0; q < 4; ++q) {
      float* sp = S + (size_t)(k0 + ii + q) * NRHS + b0 + bl;
      float4 x0 = {acc[q][0], acc[q][1], acc[q][2], acc[q][3]};
      float4 x1 = {acc[q][4], acc[q][5], acc[q][6], acc[q][7]};
      *(float4*)sp = x0; *((float4*)sp + 1) = x1;
    }
    return;
  }
  for (int q = 0; q < 4; ++q) {
    float4 x0 = {acc[q][0], acc[q][1], acc[q][2], acc[q][3]};
    float4 x1 = {acc[q][4], acc[q][5], acc[q][6], acc[q][7]};
    *(float4*)&Xl[ii + q][bl] = x0; *(float4*)&Xl[ii + q][bl + 4] = x1;
  }
  __syncthreads();
  float acc2[4][8] = {};
  for (int tch = 0; tch < NB; tch += 16) {
    for (int idx = tid; idx < 512; idx += 256) {
      int t = idx >> 5, f = idx & 31;
      *(float4*)&Aa[t][4 * f] = *(const float4*)(M + (size_t)(k0 + tch + t) * N + i0g + 4 * f);
    }
    __syncthreads();
#pragma unroll 4
    for (int t = 0; t < 16; ++t) {
      float4 a0 = *(const float4*)&Aa[t][ii];
      float4 b0v = *(const float4*)&Xl[tch + t][bl];
      float4 b1v = *(const float4*)&Xl[tch + t][bl + 4];
      float av[4] = {a0.x, a0.y, a0.z, a0.w};
      float bv[8] = {b0v.x, b0v.y, b0v.z, b0v.w, b1v.x, b1v.y, b1v.z, b1v.w};
#pragma unroll
      for (int q = 0; q < 4; ++q)
#pragma unroll
        for (int w = 0; w < 8; ++w) acc2[q][w] += av[q] * bv[w];
    }
    __syncthreads();
  }
  for (int q = 0; q < 4; ++q) {
    float* xp = X + (size_t)(i0g + ii + q) * NRHS + b0 + bl;
    float4 x0 = *(float4*)xp, x1 = *((float4*)xp + 1);
    x0.x -= acc2[q][0]; x0.y -= acc2[q][1]; x0.z -= acc2[q][2]; x0.w -= acc2[q][3];
    x1.x -= acc2[q][4]; x1.y -= acc2[q][5]; x1.z -= acc2[q][6]; x1.w -= acc2[q][7];
    *(float4*)xp = x0; *((float4*)xp + 1) = x1;
  }
}

// ---------------- denom + normalize + transpose to output ----------------
__global__ __launch_bounds__(256) void k_final(const float* __restrict__ S,
                                               const float* __restrict__ K,
                                               const float* __restrict__ a_ptr,
                                               float* __restrict__ out) {
  __shared__ float red[256];
  int b = blockIdx.x, tid = threadIdx.x;
  float s = 0.0f;
  for (int i = tid; i < N; i += 256) s += S[(size_t)i * NRHS + b] * K[(size_t)b * N + i];
  red[tid] = s; __syncthreads();
  for (int w = 128; w > 0; w >>= 1) { if (tid < w) red[tid] += red[tid + w]; __syncthreads(); }
  float inv = 1.0f / (a_ptr[0] * red[0]);
  for (int i = tid; i < N; i += 256) out[(size_t)b * N + i] = S[(size_t)i * NRHS + b] * inv;
}

extern "C" void kernel_launch(void* const* d_in, const int* in_sizes, int n_in,
                              void* d_out, int out_size, void* d_ws, size_t ws_size,
                              hipStream_t stream) {
  const float* Kb    = (const float*)d_in[0];
  const float* a     = (const float*)d_in[1];
  const float* exc   = (const float*)d_in[2];
  const float* imp   = (const float*)d_in[3];
  const float* Phi   = (const float*)d_in[4];
  const float* gamma = (const float*)d_in[5];
  float* out = (float*)d_out;

  float* M  = (float*)d_ws;                        // n*n            (64 MiB)
  float* S  = M + (size_t)N * N;                   // n*NRHS         (8 MiB)
  float* X  = S + (size_t)N * NRHS;                // n*NRHS         (8 MiB)
  float* U  = X + (size_t)N * NRHS;                // 32 * 128*128   (2 MiB)
  float* UT = U + (size_t)32 * NB * NB;            // 32 * 128*128   (2 MiB)
  float* c  = UT + (size_t)32 * NB * NB;           // scalars

  k_scalars<<<1, 256, 0, stream>>>(imp, exc, gamma, c);
  k_build_M<<<N * N / 1024, 256, 0, stream>>>(Phi, c, M);
  k_transpose<<<dim3(N / 32, NRHS / 32), 256, 0, stream>>>(Kb, S);

  // potrf(0) standalone
  k_syrk_potrf<<<1, 256, 0, stream>>>(M, U, UT, 0, -1);
  for (int k = 0; k <= 30; ++k) {
    int k0 = k * NB;
    k_trsm<<<31 - k, 256, 0, stream>>>(M, UT + (size_t)k * NB * NB, k0);
    int T = 31 - k;
    int pairs = (T * (T + 1)) / 2;   // logical block 0 = lookahead potrf(k+1)
    k_syrk_potrf<<<pairs, 256, 0, stream>>>(M, U + (size_t)(k + 1) * NB * NB,
                                            UT + (size_t)(k + 1) * NB * NB, k + 1, k0);
  }
  for (int k = 0; k < 32; ++k)
    k_fsolve<<<8 * (32 - k), 256, 0, stream>>>(S, X, M, UT + (size_t)k * NB * NB, k * NB);
  for (int k = 31; k >= 0; --k)
    k_bsolve<<<8 * (k + 1), 256, 0, stream>>>(X, S, M, U + (size_t)k * NB * NB, k * NB);
  k_final<<<NRHS, 256, 0, stream>>>(S, Kb, a, out);
}

// Round 8
// 6756.373 us; speedup vs baseline: 1.1799x; 1.1799x over previous
//
#include <hip/hip_runtime.h>

// OptNet KKT layer: out = normalize(M^{-1} K^T), M = c1*Phi + c2*I (SPD, n=4096, 512 RHS).
// Blocked fp32 Cholesky with lookahead. R8: the single potrf block was the gate (~175us).
// potrf rebuilt: 16x16 register corners (shfl factor+inverse), V stored in LDS upper
// triangle, strip-TRSM/trailing/U-assembly all as parallel GEMM phases, 512 threads.
// UT eliminated (consumers stage-transpose U). No L-diag writeback.

#define N    4096
#define NRHS 512
#define NB   128
#define TSTR2 132  // LDS tile stride
#define TSTR 136   // solve staging stride
#define BSTR 68    // 64-wide RHS tile stride

__device__ __forceinline__ int xcd_map(int bid, int nwg) {
  int x = bid & 7, i = bid >> 3;
  int q = nwg >> 3, r = nwg & 7;
  return (x < r ? x * (q + 1) : r * (q + 1) + (x - r) * q) + i;
}

// stage 128x128 tile t-major: T[t*TSTR2+r] = g[row0+r][col0+t]  (512 threads)
__device__ __forceinline__ void stage_tmajor512(const float* __restrict__ g,
                                                int row0, int col0,
                                                float* __restrict__ T, int tid) {
#pragma unroll
  for (int i = 0; i < 8; ++i) {
    int idx = tid + (i << 9);
    int r = idx >> 5, fx = idx & 31;
    const float4 v = *(const float4*)(g + (size_t)(row0 + r) * N + col0 + 4 * fx);
    int c4 = 4 * fx;
    T[(c4 + 0) * TSTR2 + r] = v.x;
    T[(c4 + 1) * TSTR2 + r] = v.y;
    T[(c4 + 2) * TSTR2 + r] = v.z;
    T[(c4 + 3) * TSTR2 + r] = v.w;
  }
}

// V_blk[r][c] (16x16 lower-tri inverse of corner), V^T stored in upper of shB diag block
__device__ __forceinline__ float vreadf(const float* __restrict__ shB,
                                        const float* __restrict__ dinv,
                                        int blk, int r, int c) {
  if (c > r) return 0.0f;
  if (c == r) return dinv[blk * 16 + r];
  return shB[(blk * 16 + c) * TSTR2 + blk * 16 + r];
}

// ---------------- scalars ----------------
__global__ __launch_bounds__(256) void k_scalars(const float* __restrict__ imp,
                                                 const float* __restrict__ exc,
                                                 const float* __restrict__ gamma,
                                                 float* __restrict__ c) {
  __shared__ float red[256];
  int tid = threadIdx.x;
  float s = 0.0f;
  for (int i = tid; i < 1024; i += 256) { float x = imp[i], y = exc[i]; s += x * x + y * y; }
  red[tid] = s; __syncthreads();
  for (int w = 128; w > 0; w >>= 1) { if (tid < w) red[tid] += red[tid + w]; __syncthreads(); }
  if (tid == 0) { c[0] = red[0] / 512.0f; c[1] = gamma[0] / 512.0f; }
}

// ---------------- M = c1*Phi + c2*I ----------------
__global__ __launch_bounds__(256) void k_build_M(const float* __restrict__ Phi,
                                                 const float* __restrict__ c,
                                                 float* __restrict__ M) {
  int idx = blockIdx.x * 256 + threadIdx.x;
  int base = idx * 4;
  float4 p = *(const float4*)(Phi + base);
  float c1 = c[0], c2 = c[1];
  float4 m;
  m.x = c1 * p.x; m.y = c1 * p.y; m.z = c1 * p.z; m.w = c1 * p.w;
  int r = base >> 12, c0 = base & (N - 1);
  if (r == c0)     m.x += c2;
  if (r == c0 + 1) m.y += c2;
  if (r == c0 + 2) m.z += c2;
  if (r == c0 + 3) m.w += c2;
  *(float4*)(M + base) = m;
}

// ---------------- S[i][b] = K[b][i] ----------------
__global__ __launch_bounds__(256) void k_transpose(const float* __restrict__ K,
                                                   float* __restrict__ S) {
  __shared__ float t[32][33];
  int bi = blockIdx.x, bb = blockIdx.y;
  int tx = threadIdx.x & 31, ty = threadIdx.x >> 5;
  for (int r = 0; r < 4; ++r)
    t[ty + 8 * r][tx] = K[(size_t)(bb * 32 + ty + 8 * r) * N + bi * 32 + tx];
  __syncthreads();
  for (int r = 0; r < 4; ++r)
    S[(size_t)(bi * 32 + ty + 8 * r) * NRHS + bb * 32 + tx] = t[tx][ty + 8 * r];
}

// ---------------- fused syrk(panel k0) + lookahead potrf(kdiag) ----------------
// 512 threads. logical block 0: potrf role; >=1: trailing syrk tile (lower tri).
__global__ __launch_bounds__(512, 2) void k_syrk_potrf(float* __restrict__ M,
                                                       float* __restrict__ U,
                                                       int kdiag, int k0) {
  __shared__ float shA[NB * TSTR2];   // syrk Pa (t-major) / potrf panel P (t-major)
  __shared__ float shB[NB * TSTR2];   // syrk Pb (t-major) / potrf diag D+L (row-major)
  __shared__ float Wl[7][16][17];
  __shared__ float dinv[NB];
  int tid = threadIdx.x;
  int p = (gridDim.x > 1) ? xcd_map(blockIdx.x, gridDim.x) : 0;
  int rr = (tid >> 4) * 4, cc = (tid & 15) * 8;

  if (p > 0) {
    // ================= syrk role: C(br,bc) -= P_br P_bc^T =================
    int br = (int)((sqrtf(8.f * (float)p + 1.f) - 1.f) * 0.5f);
    while (((br + 1) * (br + 2)) / 2 <= p) ++br;
    while ((br * (br + 1)) / 2 > p) --br;
    int bc = p - (br * (br + 1)) / 2;
    int t0 = kdiag * NB;
    int r0 = t0 + br * NB, c0 = t0 + bc * NB;
    stage_tmajor512(M, r0, k0, shA, tid);
    stage_tmajor512(M, c0, k0, shB, tid);
    __syncthreads();
    float acc[4][8] = {};
#pragma unroll 2
    for (int t = 0; t < NB; ++t) {
      const float4 a0 = *(const float4*)&shA[t * TSTR2 + rr];
      const float4 b0 = *(const float4*)&shB[t * TSTR2 + cc];
      const float4 b1 = *(const float4*)&shB[t * TSTR2 + cc + 4];
      float av[4] = {a0.x, a0.y, a0.z, a0.w};
      float bv[8] = {b0.x, b0.y, b0.z, b0.w, b1.x, b1.y, b1.z, b1.w};
#pragma unroll
      for (int q = 0; q < 4; ++q)
#pragma unroll
        for (int w = 0; w < 8; ++w) acc[q][w] += av[q] * bv[w];
    }
    for (int q = 0; q < 4; ++q) {
      float* mp = M + (size_t)(r0 + rr + q) * N + c0 + cc;
      float4 x0 = *(float4*)mp, x1 = *((float4*)mp + 1);
      x0.x -= acc[q][0]; x0.y -= acc[q][1]; x0.z -= acc[q][2]; x0.w -= acc[q][3];
      x1.x -= acc[q][4]; x1.y -= acc[q][5]; x1.z -= acc[q][6]; x1.w -= acc[q][7];
      *(float4*)mp = x0; *((float4*)mp + 1) = x1;
    }
    return;
  }

  // ================= potrf role =================
  int kr = kdiag * NB;
  // stage diag tile D row-major into shB
#pragma unroll
  for (int i = 0; i < 8; ++i) {
    int idx = tid + (i << 9);
    int r = idx >> 5, fx = idx & 31;
    *(float4*)&shB[r * TSTR2 + 4 * fx] =
        *(const float4*)(M + (size_t)(kr + r) * N + kr + 4 * fx);
  }
  if (k0 >= 0) {  // D -= P P^T, P = trsm'd panel M[kr.., k0..]
    stage_tmajor512(M, kr, k0, shA, tid);
    __syncthreads();
    float accd[4][8] = {};
#pragma unroll 2
    for (int t = 0; t < NB; ++t) {
      const float4 a0 = *(const float4*)&shA[t * TSTR2 + rr];
      const float4 b0 = *(const float4*)&shA[t * TSTR2 + cc];
      const float4 b1 = *(const float4*)&shA[t * TSTR2 + cc + 4];
      float av[4] = {a0.x, a0.y, a0.z, a0.w};
      float bv[8] = {b0.x, b0.y, b0.z, b0.w, b1.x, b1.y, b1.z, b1.w};
#pragma unroll
      for (int q = 0; q < 4; ++q)
#pragma unroll
        for (int w = 0; w < 8; ++w) accd[q][w] += av[q] * bv[w];
    }
    __syncthreads();
#pragma unroll
    for (int q = 0; q < 4; ++q)
#pragma unroll
      for (int w = 0; w < 8; ++w)
        shB[(rr + q) * TSTR2 + cc + w] -= accd[q][w];
  }
  __syncthreads();

  // ---- factor: 8 panels of 16 columns ----
  int l = tid;
#pragma unroll 1
  for (int pp = 0; pp < 8; ++pp) {
    const int b0 = 16 * pp;
    if (tid < 16) {
      // 16x16 corner factor in registers (shfl)
      float r[16];
#pragma unroll
      for (int t = 0; t < 16; ++t) r[t] = shB[(b0 + l) * TSTR2 + b0 + t];
#pragma unroll
      for (int j = 0; j < 16; ++j) {
        float d = __shfl(r[j], j);
        float inv = rsqrtf(d);
        if (l == j) r[j] = d * inv;
        else if (l > j) r[j] *= inv;
        if (l == 0) dinv[b0 + j] = inv;
#pragma unroll
        for (int t = j + 1; t < 16; ++t) {
          float Ltj = __shfl(r[j], t);
          if (l >= t) r[t] -= r[j] * Ltj;
        }
      }
#pragma unroll
      for (int t = 0; t < 16; ++t) if (t <= l) shB[(b0 + l) * TSTR2 + b0 + t] = r[t];
      // corner inverse: lane l = column l of V (natural zeros above diag)
      float x[16];
#pragma unroll
      for (int i = 0; i < 16; ++i) {
        float s = (l == i) ? 1.0f : 0.0f;
#pragma unroll
        for (int t = 0; t < 16; ++t)
          if (t < i) s -= __shfl(r[t], i) * x[t];
        x[i] = s * dinv[b0 + i];
      }
      // store V^T strict-lower into the (unused) upper of the diag block
#pragma unroll
      for (int i = 0; i < 16; ++i)
        if (i > l) shB[(b0 + l) * TSTR2 + b0 + i] = x[i];
    }
    __syncthreads();
    const int base = b0 + 16, nbl = NB - base;
    if (nbl > 0) {
      // strip TRSM as GEMM: L[r][b0+c] = sum_{t<=c} A[r][b0+t] * V[c][t]
      const int cnt = nbl * 16;
      float pv[4];
#pragma unroll
      for (int e = 0; e < 4; ++e) {
        int idx = tid + e * 512;
        if (idx < cnt) {
          int r2 = base + (idx >> 4), c2 = idx & 15;
          float s = 0.0f;
          for (int t = 0; t <= c2; ++t)
            s += shB[r2 * TSTR2 + b0 + t] * vreadf(shB, dinv, pp, c2, t);
          pv[e] = s;
        }
      }
      __syncthreads();
#pragma unroll
      for (int e = 0; e < 4; ++e) {
        int idx = tid + e * 512;
        if (idx < cnt) {
          int r2 = base + (idx >> 4), c2 = idx & 15;
          shB[r2 * TSTR2 + b0 + c2] = pv[e];
        }
      }
      __syncthreads();
      // rank-16 trailing update (lower incl diag)
      const int tot = nbl * nbl;
      for (int idx = tid; idx < tot; idx += 512) {
        const int i = idx / nbl, j = idx - i * nbl;
        if (j <= i) {
          const float* ai = &shB[(base + i) * TSTR2 + b0];
          const float* bj = &shB[(base + j) * TSTR2 + b0];
          float4 a0 = *(const float4*)ai,       a1 = *(const float4*)(ai + 4);
          float4 a2 = *(const float4*)(ai + 8), a3 = *(const float4*)(ai + 12);
          float4 c0 = *(const float4*)bj,       c1 = *(const float4*)(bj + 4);
          float4 c2 = *(const float4*)(bj + 8), c3 = *(const float4*)(bj + 12);
          float s = a0.x*c0.x + a0.y*c0.y + a0.z*c0.z + a0.w*c0.w
                  + a1.x*c1.x + a1.y*c1.y + a1.z*c1.z + a1.w*c1.w
                  + a2.x*c2.x + a2.y*c2.y + a2.z*c2.z + a2.w*c2.w
                  + a3.x*c3.x + a3.y*c3.y + a3.z*c3.z + a3.w*c3.w;
          shB[(base + i) * TSTR2 + base + j] -= s;
        }
      }
      __syncthreads();
    }
  }

  // ---- write U diag blocks (V, with upper zeros) ----
  for (int e = tid; e < 8 * 256; e += 512) {
    int blk = e >> 8, el = e & 255;
    int r2 = el >> 4, c2 = el & 15;
    U[(size_t)(16 * blk + r2) * NB + 16 * blk + c2] = vreadf(shB, dinv, blk, r2, c2);
  }
  // ---- zero U upper blocks (bi < bj): 28 blocks ----
  for (int e = tid; e < 28 * 256; e += 512) {
    int q2 = e >> 8;
    int bi = 0;
    while (q2 >= 7 - bi) { q2 -= 7 - bi; ++bi; }
    int bj = bi + 1 + q2;
    int el = e & 255, r2 = el >> 4, c2 = el & 15;
    U[(size_t)(16 * bi + r2) * NB + 16 * bj + c2] = 0.0f;
  }
  __syncthreads();

  // ---- assemble off-diag U by block diagonals: U_ij = -V_i * (sum_t L_it U_tj) ----
#pragma unroll 1
  for (int d = 1; d <= 7; ++d) {
    const int nb = 8 - d;
    for (int e = tid; e < nb * 256; e += 512) {
      int pr = e >> 8, j = pr, i2 = j + d;
      int el = e & 255, rW = el >> 4, cW = el & 15;
      float s = 0.0f;
      for (int u = cW; u < 16; ++u)    // t == j term: V_j from LDS
        s += shB[(16 * i2 + rW) * TSTR2 + 16 * j + u] * vreadf(shB, dinv, j, u, cW);
      for (int t = j + 1; t < i2; ++t) // t > j: strips from global U (earlier diagonals)
        for (int u = 0; u < 16; ++u)
          s += shB[(16 * i2 + rW) * TSTR2 + 16 * t + u] *
               U[(size_t)(16 * t + u) * NB + 16 * j + cW];
      Wl[pr][rW][cW] = s;
    }
    __syncthreads();
    for (int e = tid; e < nb * 256; e += 512) {
      int pr = e >> 8, j = pr, i2 = j + d;
      int el = e & 255, rU = el >> 4, cU = el & 15;
      float s = 0.0f;
      for (int u = 0; u <= rU; ++u)
        s += vreadf(shB, dinv, i2, rU, u) * Wl[pr][u][cU];
      U[(size_t)(16 * i2 + rU) * NB + 16 * j + cU] = -s;
    }
    __syncthreads();
  }
}

// ---------------- panel TRSM as GEMM: P := P_old * U^T (512 threads) ----------------
__global__ __launch_bounds__(512, 2) void k_trsm(float* __restrict__ M,
                                                 const float* __restrict__ Ug, int k0) {
  __shared__ float shU[NB * TSTR2];   // shU[t][j] = U[j][t]
  __shared__ float shA[NB * TSTR2];   // t-major A tile
  int tid = threadIdx.x;
  int r0 = k0 + NB + blockIdx.x * NB;
#pragma unroll
  for (int i = 0; i < 8; ++i) {        // stage U rows, transpose into LDS
    int idx = tid + (i << 9);
    int j = idx >> 5, fx = idx & 31;
    const float4 v = *(const float4*)(Ug + (size_t)j * NB + 4 * fx);
    int c4 = 4 * fx;
    shU[(c4 + 0) * TSTR2 + j] = v.x;
    shU[(c4 + 1) * TSTR2 + j] = v.y;
    shU[(c4 + 2) * TSTR2 + j] = v.z;
    shU[(c4 + 3) * TSTR2 + j] = v.w;
  }
  stage_tmajor512(M, r0, k0, shA, tid);
  __syncthreads();
  int i0 = (tid >> 4) * 4, j0 = (tid & 15) * 8;
  float acc[4][8] = {};
#pragma unroll 2
  for (int t = 0; t < NB; ++t) {
    const float4 a0 = *(const float4*)&shA[t * TSTR2 + i0];
    const float4 u0 = *(const float4*)&shU[t * TSTR2 + j0];
    const float4 u1 = *(const float4*)&shU[t * TSTR2 + j0 + 4];
    float av[4] = {a0.x, a0.y, a0.z, a0.w};
    float uv[8] = {u0.x, u0.y, u0.z, u0.w, u1.x, u1.y, u1.z, u1.w};
#pragma unroll
    for (int q = 0; q < 4; ++q)
#pragma unroll
      for (int w = 0; w < 8; ++w) acc[q][w] += av[q] * uv[w];
  }
  for (int q = 0; q < 4; ++q) {
    float* mp = M + (size_t)(r0 + i0 + q) * N + k0 + j0;
    float4 x0 = {acc[q][0], acc[q][1], acc[q][2], acc[q][3]};
    float4 x1 = {acc[q][4], acc[q][5], acc[q][6], acc[q][7]};
    *(float4*)mp = x0; *((float4*)mp + 1) = x1;
  }
}

// ---------------- fused forward solve step k (1-D grid, XCD-chunked) ----------------
__global__ __launch_bounds__(256) void k_fsolve(float* __restrict__ S,
                                                float* __restrict__ X,
                                                const float* __restrict__ M,
                                                const float* __restrict__ Uk,
                                                int k0) {
  __shared__ float Xl[NB][BSTR];
  __shared__ float Aa[16][TSTR];
  __shared__ float Bb[16][BSTR];
  int tid = threadIdx.x;
  int id = xcd_map(blockIdx.x, gridDim.x);
  int d = id >> 3;
  int b0 = (id & 7) * 64;
  int i0g = k0 + d * NB;
  int ii = (tid >> 3) * 4, bl = (tid & 7) * 8;
  float acc[4][8] = {};
  for (int tch = 0; tch < NB; tch += 16) {
#pragma unroll
    for (int it = 0; it < 2; ++it) {   // Aa[t][j] = U[j][tch+t]
      int idx = tid + it * 256;
      int j = idx >> 2, f4 = idx & 3;
      const float4 v = *(const float4*)(Uk + (size_t)j * NB + tch + 4 * f4);
      Aa[4 * f4 + 0][j] = v.x; Aa[4 * f4 + 1][j] = v.y;
      Aa[4 * f4 + 2][j] = v.z; Aa[4 * f4 + 3][j] = v.w;
    }
    {
      int t = tid >> 4, f = tid & 15;
      *(float4*)&Bb[t][4 * f] = *(const float4*)(S + (size_t)(k0 + tch + t) * NRHS + b0 + 4 * f);
    }
    __syncthreads();
#pragma unroll 4
    for (int t = 0; t < 16; ++t) {
      float4 a0 = *(const float4*)&Aa[t][ii];
      float4 b0v = *(const float4*)&Bb[t][bl];
      float4 b1v = *(const float4*)&Bb[t][bl + 4];
      float av[4] = {a0.x, a0.y, a0.z, a0.w};
      float bv[8] = {b0v.x, b0v.y, b0v.z, b0v.w, b1v.x, b1v.y, b1v.z, b1v.w};
#pragma unroll
      for (int q = 0; q < 4; ++q)
#pragma unroll
        for (int w = 0; w < 8; ++w) acc[q][w] += av[q] * bv[w];
    }
    __syncthreads();
  }
  if (d == 0) {
    for (int q = 0; q < 4; ++q) {
      float* xp = X + (size_t)(k0 + ii + q) * NRHS + b0 + bl;
      float4 x0 = {acc[q][0], acc[q][1], acc[q][2], acc[q][3]};
      float4 x1 = {acc[q][4], acc[q][5], acc[q][6], acc[q][7]};
      *(float4*)xp = x0; *((float4*)xp + 1) = x1;
    }
    return;
  }
  for (int q = 0; q < 4; ++q) {
    float4 x0 = {acc[q][0], acc[q][1], acc[q][2], acc[q][3]};
    float4 x1 = {acc[q][4], acc[q][5], acc[q][6], acc[q][7]};
    *(float4*)&Xl[ii + q][bl] = x0; *(float4*)&Xl[ii + q][bl + 4] = x1;
  }
  __syncthreads();
  float acc2[4][8] = {};
  for (int tch = 0; tch < NB; tch += 16) {
    for (int idx = tid; idx < 512; idx += 256) {
      int r = idx >> 2, q = idx & 3;
      const float4 v = *(const float4*)(M + (size_t)(i0g + r) * N + k0 + tch + 4 * q);
      Aa[4 * q + 0][r] = v.x; Aa[4 * q + 1][r] = v.y;
      Aa[4 * q + 2][r] = v.z; Aa[4 * q + 3][r] = v.w;
    }
    __syncthreads();
#pragma unroll 4
    for (int t = 0; t < 16; ++t) {
      float4 a0 = *(const float4*)&Aa[t][ii];
      float4 b0v = *(const float4*)&Xl[tch + t][bl];
      float4 b1v = *(const float4*)&Xl[tch + t][bl + 4];
      float av[4] = {a0.x, a0.y, a0.z, a0.w};
      float bv[8] = {b0v.x, b0v.y, b0v.z, b0v.w, b1v.x, b1v.y, b1v.z, b1v.w};
#pragma unroll
      for (int q = 0; q < 4; ++q)
#pragma unroll
        for (int w = 0; w < 8; ++w) acc2[q][w] += av[q] * bv[w];
    }
    __syncthreads();
  }
  for (int q = 0; q < 4; ++q) {
    float* sp = S + (size_t)(i0g + ii + q) * NRHS + b0 + bl;
    float4 x0 = *(float4*)sp, x1 = *((float4*)sp + 1);
    x0.x -= acc2[q][0]; x0.y -= acc2[q][1]; x0.z -= acc2[q][2]; x0.w -= acc2[q][3];
    x1.x -= acc2[q][4]; x1.y -= acc2[q][5]; x1.z -= acc2[q][6]; x1.w -= acc2[q][7];
    *(float4*)sp = x0; *((float4*)sp + 1) = x1;
  }
}

// ---------------- fused backward solve step k (1-D grid, XCD-chunked) ----------------
__global__ __launch_bounds__(256) void k_bsolve(float* __restrict__ X,
                                                float* __restrict__ S,
                                                const float* __restrict__ M,
                                                const float* __restrict__ Uk,
                                                int k0) {
  __shared__ float Xl[NB][BSTR];
  __shared__ float Aa[16][TSTR];
  __shared__ float Bb[16][BSTR];
  int tid = threadIdx.x;
  int id = xcd_map(blockIdx.x, gridDim.x);
  int d = id >> 3;
  int b0 = (id & 7) * 64;
  int i0g = k0 - d * NB;
  int ii = (tid >> 3) * 4, bl = (tid & 7) * 8;
  float acc[4][8] = {};
  for (int tch = 0; tch < NB; tch += 16) {
    for (int idx = tid; idx < 512; idx += 256) {
      int t = idx >> 5, f = idx & 31;
      *(float4*)&Aa[t][4 * f] = *(const float4*)(Uk + (size_t)(tch + t) * NB + 4 * f);
    }
    {
      int t = tid >> 4, f = tid & 15;
      *(float4*)&Bb[t][4 * f] = *(const float4*)(X + (size_t)(k0 + tch + t) * NRHS + b0 + 4 * f);
    }
    __syncthreads();
#pragma unroll 4
    for (int t = 0; t < 16; ++t) {
      float4 a0 = *(const float4*)&Aa[t][ii];
      float4 b0v = *(const float4*)&Bb[t][bl];
      float4 b1v = *(const float4*)&Bb[t][bl + 4];
      float av[4] = {a0.x, a0.y, a0.z, a0.w};
      float bv[8] = {b0v.x, b0v.y, b0v.z, b0v.w, b1v.x, b1v.y, b1v.z, b1v.w};
#pragma unroll
      for (int q = 0; q < 4; ++q)
#pragma unroll
        for (int w = 0; w < 8; ++w) acc[q][w] += av[q] * bv[w];
    }
    __syncthreads();
  }
  if (d == 0) {
    for (int q = 0; q < 4; ++q) {
      float* sp = S + (size_t)(k0 + ii + q) * NRHS + b0 + bl;
      float4 x0 = {acc[q][0], acc[q][1], acc[q][2], acc[q][3]};
      float4 x1 = {acc[q][4], acc[q][5], acc[q][6], acc[q][7]};
      *(float4*)sp = x0; *((float4*)sp + 1) = x1;
    }
    return;
  }
  for (int q = 0; q < 4; ++q) {
    float4 x0 = {acc[q][0], acc[q][1], acc[q][2], acc[q][3]};
    float4 x1 = {acc[q][4], acc[q][5], acc[q][6], acc[q][7]};
    *(float4*)&Xl[ii + q][bl] = x0; *(float4*)&Xl[ii + q][bl + 4] = x1;
  }
  __syncthreads();
  float acc2[4][8] = {};
  for (int tch = 0; tch < NB; tch += 16) {
    for (int idx = tid; idx < 512; idx += 256) {
      int t = idx >> 5, f = idx & 31;
      *(float4*)&Aa[t][4 * f] = *(const float4*)(M + (size_t)(k0 + tch + t) * N + i0g + 4 * f);
    }
    __syncthreads();
#pragma unroll 4
    for (int t = 0; t < 16; ++t) {
      float4 a0 = *(const float4*)&Aa[t][ii];
      float4 b0v = *(const float4*)&Xl[tch + t][bl];
      float4 b1v = *(const float4*)&Xl[tch + t][bl + 4];
      float av[4] = {a0.x, a0.y, a0.z, a0.w};
      float bv[8] = {b0v.x, b0v.y, b0v.z, b0v.w, b1v.x, b1v.y, b1v.z, b1v.w};
#pragma unroll
      for (int q = 0; q < 4; ++q)
#pragma unroll
        for (int w = 0; w < 8; ++w) acc2[q][w] += av[q] * bv[w];
    }
    __syncthreads();
  }
  for (int q = 0; q < 4; ++q) {
    float* xp = X + (size_t)(i0g + ii + q) * NRHS + b0 + bl;
    float4 x0 = *(float4*)xp, x1 = *((float4*)xp + 1);
    x0.x -= acc2[q][0]; x0.y -= acc2[q][1]; x0.z -= acc2[q][2]; x0.w -= acc2[q][3];
    x1.x -= acc2[q][4]; x1.y -= acc2[q][5]; x1.z -= acc2[q][6]; x1.w -= acc2[q][7];
    *(float4*)xp = x0; *((float4*)xp + 1) = x1;
  }
}

// ---------------- denom + normalize + transpose to output ----------------
__global__ __launch_bounds__(256) void k_final(const float* __restrict__ S,
                                               const float* __restrict__ K,
                                               const float* __restrict__ a_ptr,
                                               float* __restrict__ out) {
  __shared__ float red[256];
  int b = blockIdx.x, tid = threadIdx.x;
  float s = 0.0f;
  for (int i = tid; i < N; i += 256) s += S[(size_t)i * NRHS + b] * K[(size_t)b * N + i];
  red[tid] = s; __syncthreads();
  for (int w = 128; w > 0; w >>= 1) { if (tid < w) red[tid] += red[tid + w]; __syncthreads(); }
  float inv = 1.0f / (a_ptr[0] * red[0]);
  for (int i = tid; i < N; i += 256) out[(size_t)b * N + i] = S[(size_t)i * NRHS + b] * inv;
}

extern "C" void kernel_launch(void* const* d_in, const int* in_sizes, int n_in,
                              void* d_out, int out_size, void* d_ws, size_t ws_size,
                              hipStream_t stream) {
  const float* Kb    = (const float*)d_in[0];
  const float* a     = (const float*)d_in[1];
  const float* exc   = (const float*)d_in[2];
  const float* imp   = (const float*)d_in[3];
  const float* Phi   = (const float*)d_in[4];
  const float* gamma = (const float*)d_in[5];
  float* out = (float*)d_out;

  float* M  = (float*)d_ws;                        // n*n            (64 MiB)
  float* S  = M + (size_t)N * N;                   // n*NRHS         (8 MiB)
  float* X  = S + (size_t)N * NRHS;                // n*NRHS         (8 MiB)
  float* U  = X + (size_t)N * NRHS;                // 32 * 128*128   (2 MiB)
  float* c  = U + (size_t)32 * NB * NB;            // scalars

  k_scalars<<<1, 256, 0, stream>>>(imp, exc, gamma, c);
  k_build_M<<<N * N / 1024, 256, 0, stream>>>(Phi, c, M);
  k_transpose<<<dim3(N / 32, NRHS / 32), 256, 0, stream>>>(Kb, S);

  // potrf(0) standalone
  k_syrk_potrf<<<1, 512, 0, stream>>>(M, U, 0, -1);
  for (int k = 0; k <= 30; ++k) {
    int k0 = k * NB;
    k_trsm<<<31 - k, 512, 0, stream>>>(M, U + (size_t)k * NB * NB, k0);
    int T = 31 - k;
    int pairs = (T * (T + 1)) / 2;   // logical block 0 = lookahead potrf(k+1)
    k_syrk_potrf<<<pairs, 512, 0, stream>>>(M, U + (size_t)(k + 1) * NB * NB, k + 1, k0);
  }
  for (int k = 0; k < 32; ++k)
    k_fsolve<<<8 * (32 - k), 256, 0, stream>>>(S, X, M, U + (size_t)k * NB * NB, k * NB);
  for (int k = 31; k >= 0; --k)
    k_bsolve<<<8 * (k + 1), 256, 0, stream>>>(X, S, M, U + (size_t)k * NB * NB, k * NB);
  k_final<<<NRHS, 256, 0, stream>>>(S, Kb, a, out);
}